// Round 1
// baseline (1286.608 us; speedup 1.0000x reference)
//
#include <hip/hip_runtime.h>
#include <math.h>

// ---------------------------------------------------------------------------
// Problem constants (B=8, N1=128, N2=256, D=128, L=3, NH=54)
// ---------------------------------------------------------------------------
#define BB 8
#define N1C 128
#define N2C 256
#define DC 128
#define NHC 54

// ---------------------------------------------------------------------------
// Reductions (wave64)
// ---------------------------------------------------------------------------
__device__ __forceinline__ float wredSum(float v) {
#pragma unroll
  for (int o = 32; o > 0; o >>= 1) v += __shfl_down(v, o);
  return v;
}
__device__ __forceinline__ float wredMax(float v) {
#pragma unroll
  for (int o = 32; o > 0; o >>= 1) v = fmaxf(v, __shfl_down(v, o));
  return v;
}
__device__ float blockSum(float v) {
  __shared__ float red[9];
  v = wredSum(v);
  int lane = threadIdx.x & 63, wid = threadIdx.x >> 6;
  __syncthreads();
  if (lane == 0) red[wid] = v;
  __syncthreads();
  if (threadIdx.x == 0) {
    float s = 0.f;
    int nw = (blockDim.x + 63) >> 6;
    for (int i = 0; i < nw; ++i) s += red[i];
    red[8] = s;
  }
  __syncthreads();
  return red[8];
}
__device__ float blockMax(float v) {
  __shared__ float redm[9];
  v = wredMax(v);
  int lane = threadIdx.x & 63, wid = threadIdx.x >> 6;
  __syncthreads();
  if (lane == 0) redm[wid] = v;
  __syncthreads();
  if (threadIdx.x == 0) {
    float s = -INFINITY;
    int nw = (blockDim.x + 63) >> 6;
    for (int i = 0; i < nw; ++i) s = fmaxf(s, redm[i]);
    redm[8] = s;
  }
  __syncthreads();
  return redm[8];
}

// ---------------------------------------------------------------------------
// Generic linear: Y = act(X @ W + bias).  X [rows][K], W [K][Dout] (row-major,
// optionally per-batch with stride wbs), 8 rows per block staged in LDS.
// trans=1 stores Y[b][d][row_in_batch] (for the transposed V features).
// ---------------------------------------------------------------------------
template <int RB>
__global__ void k_linear(const float* __restrict__ X, const float* __restrict__ W,
                         const float* __restrict__ bias, float* __restrict__ Y,
                         int K, int Dout, int rows, int rpb, long wbs, int act,
                         int trans) {
  int r0 = blockIdx.x * RB;
  extern __shared__ float xs[];  // RB*K
  for (int t = threadIdx.x; t < RB * K; t += blockDim.x) {
    int rr = r0 + t / K;
    xs[t] = (rr < rows) ? X[(long)rr * K + (t % K)] : 0.f;
  }
  __syncthreads();
  int b = r0 / rpb;  // RB always divides rpb in our uses
  const float* Wb = W + (long)b * wbs;
  for (int d = threadIdx.x; d < Dout; d += blockDim.x) {
    float acc[RB];
#pragma unroll
    for (int r = 0; r < RB; ++r) acc[r] = 0.f;
    for (int k = 0; k < K; ++k) {
      float wv = Wb[(long)k * Dout + d];
#pragma unroll
      for (int r = 0; r < RB; ++r) acc[r] += xs[r * K + k] * wv;
    }
    float bv = bias ? bias[d] : 0.f;
#pragma unroll
    for (int r = 0; r < RB; ++r) {
      int rr = r0 + r;
      if (rr < rows) {
        float v = acc[r] + bv;
        if (act) v = fmaxf(v, 0.f);
        if (!trans) {
          Y[(long)rr * Dout + d] = v;
        } else {
          int rin = rr - b * rpb;
          Y[((long)b * Dout + d) * rpb + rin] = v;
        }
      }
    }
  }
}

// ---------------------------------------------------------------------------
// ea[b,j,k] = e1_j . nt_k + nt_j . e1_k   (symmetrized attention logits)
// ---------------------------------------------------------------------------
__global__ void k_ea(const float* __restrict__ E1p, const float* __restrict__ NTp,
                     float* __restrict__ EAp, int N) {
  const int D = DC;
  int b = blockIdx.z;
  int j0 = blockIdx.y * 16, k0 = blockIdx.x * 16;
  int tj = threadIdx.y, tk = threadIdx.x;
  __shared__ float e1j[16][17], ntj[16][17], e1k[16][17], ntk[16][17];
  const float* E1b = E1p + (long)b * N * D;
  const float* NTb = NTp + (long)b * N * D;
  float acc = 0.f;
  for (int kk = 0; kk < D; kk += 16) {
    e1j[tj][tk] = E1b[(long)(j0 + tj) * D + kk + tk];
    ntj[tj][tk] = NTb[(long)(j0 + tj) * D + kk + tk];
    e1k[tj][tk] = E1b[(long)(k0 + tj) * D + kk + tk];
    ntk[tj][tk] = NTb[(long)(k0 + tj) * D + kk + tk];
    __syncthreads();
#pragma unroll
    for (int t = 0; t < 16; ++t)
      acc += e1j[tj][t] * ntk[tk][t] + ntj[tj][t] * e1k[tk][t];
    __syncthreads();
  }
  EAp[(long)b * N * N + (long)(j0 + tj) * N + k0 + tk] = acc;
}

// masked softmax over last dim, times adj (in-place capable)
__global__ void k_softmax(const float* __restrict__ EAin,
                          const float* __restrict__ ADJ, float* __restrict__ AW,
                          int N) {
  long row = blockIdx.x;
  int k = threadIdx.x;
  float a = ADJ[row * (long)N + k];
  float e = EAin[row * (long)N + k];
  float val = (a > 1e-6f) ? e : -9e15f;
  float m = blockMax(val);
  float ex = expf(val - m);
  float s = blockSum(ex);
  AW[row * (long)N + k] = ex / s * a;
}

// gated residual: y = g*x + (1-g)*out,  g = sigmoid([x,out].gw + gb)
__global__ void k_gate(const float* __restrict__ X, const float* __restrict__ OUT,
                       const float* __restrict__ GW, const float* __restrict__ GB,
                       float* __restrict__ Y) {
  const int D = DC;
  long r = blockIdx.x;
  int d = threadIdx.x;
  float x = X[r * D + d], o = OUT[r * D + d];
  float s = blockSum(x * GW[d] + o * GW[D + d]);
  float g = 1.f / (1.f + expf(-(s + GB[0])));
  Y[r * D + d] = g * x + (1.f - g) * o;
}

// adj12 from positions
__global__ void k_adj12(const float* __restrict__ LP, const float* __restrict__ TP,
                        float* __restrict__ AD) {
  long idx = (long)blockIdx.x * blockDim.x + threadIdx.x;
  if (idx >= (long)BB * N1C * N2C) return;
  int j = idx & (N2C - 1);
  long t = idx >> 8;
  int i = (int)(t & (N1C - 1));
  int b = (int)(t >> 7);
  float dx = LP[((long)b * N1C + i) * 3 + 0] - TP[((long)b * N2C + j) * 3 + 0];
  float dy = LP[((long)b * N1C + i) * 3 + 1] - TP[((long)b * N2C + j) * 3 + 1];
  float dz = LP[((long)b * N1C + i) * 3 + 2] - TP[((long)b * N2C + j) * 3 + 2];
  float d = sqrtf(dx * dx + dy * dy + dz * dz + 1e-10f);
  if (d < 0.5f) d = 1e10f;
  AD[idx] = (d <= 5.0f && d > 1e-3f) ? 1.f : 0.f;
}

// msg = relu(t1 + max_j(m2[j]*ev[i,j]))
__global__ void k_msg(const float* __restrict__ T1, const float* __restrict__ M2,
                      const float* __restrict__ EV, float* __restrict__ MSG,
                      int Ni, int Nj, long ev_bs, long ev_is, long ev_js) {
  const int D = DC;
  int i = blockIdx.x, b = blockIdx.y, d = threadIdx.x;
  extern __shared__ float evs[];
  for (int j = d; j < Nj; j += blockDim.x)
    evs[j] = EV[(long)b * ev_bs + (long)i * ev_is + (long)j * ev_js];
  __syncthreads();
  const float* M2b = M2 + ((long)b * Nj) * D;
  float m = -INFINITY;
  for (int j = 0; j < Nj; ++j) m = fmaxf(m, M2b[(long)j * D + d] * evs[j]);
  long idx = ((long)b * Ni + i) * D + d;
  MSG[idx] = fmaxf(T1[idx] + m, 0.f);
}

// GRU combine
__global__ void k_gru(const float* __restrict__ GI, const float* __restrict__ GH,
                      const float* __restrict__ A1, float* __restrict__ Y) {
  const int D = DC;
  long r = blockIdx.x;
  int d = threadIdx.x;
  long base = r * 3 * D;
  float ir = GI[base + d], iz = GI[base + D + d], inn = GI[base + 2 * D + d];
  float hr = GH[base + d], hz = GH[base + D + d], hn = GH[base + 2 * D + d];
  float rg = 1.f / (1.f + expf(-(ir + hr)));
  float zg = 1.f / (1.f + expf(-(iz + hz)));
  float ng = tanhf(inn + rg * hn);
  float a = A1[r * D + d];
  Y[r * D + d] = (1.f - zg) * ng + zg * a;
}

// transpose [R][C] -> [C][R]
__global__ void k_transpose(const float* __restrict__ in, float* __restrict__ out,
                            int R, int C) {
  for (long idx = (long)blockIdx.x * blockDim.x + threadIdx.x; idx < (long)R * C;
       idx += (long)gridDim.x * blockDim.x) {
    int r = (int)(idx / C), c = (int)(idx % C);
    out[(long)c * R + r] = in[idx];
  }
}

// ---------------------------------------------------------------------------
// Pairwise physics + analytic grad/Hessian partials.
// Per (b,i) block, 256 threads (j).  Writes 8 partials per (b,i):
// [vdw, hb, metal, hp, Sx, Sy, Sz, d2]
// ---------------------------------------------------------------------------
__global__ __launch_bounds__(256) void k_pair(
    const float* __restrict__ UA, const float* __restrict__ VAT,
    const float* __restrict__ UB, const float* __restrict__ VBT,
    const float* __restrict__ AW2, const float* __restrict__ AB2,
    const float* __restrict__ BW2, const float* __restrict__ BB2,
    const float* __restrict__ LP, const float* __restrict__ TP,
    const float* __restrict__ LVDW, const float* __restrict__ TVDW,
    const float* __restrict__ LNM, const float* __restrict__ TNM,
    const float* __restrict__ II, const float* __restrict__ HBC,
    const float* __restrict__ HPC, float* __restrict__ PART) {
  const int D = DC, N1 = N1C, N2 = N2C;
  int i = blockIdx.x, b = blockIdx.y, j = threadIdx.x;
  __shared__ float ua[128], ub[128], wa2[128], wb2[128];
  if (j < 128) {
    long rb = ((long)b * N1 + i) * D + j;
    ua[j] = UA[rb];
    ub[j] = UB[rb];
    wa2[j] = AW2[j];
    wb2[j] = BW2[j];
  }
  __syncthreads();
  const float* vat = VAT + (long)b * D * N2;
  const float* vbt = VBT + (long)b * D * N2;
  float dotA = 0.f, dotB = 0.f;
  for (int d = 0; d < D; ++d) {
    dotA += fmaxf(ua[d] + vat[(long)d * N2 + j], 0.f) * wa2[d];
    dotB += fmaxf(ub[d] + vbt[(long)d * N2 + j], 0.f) * wb2[d];
  }
  float A_raw = 1.f / (1.f + expf(-(dotA + AB2[0])));
  float A_vdw = A_raw * (0.0356f - 0.0178f) + 0.0178f;
  float B_raw = tanhf(dotB + BB2[0]) * 0.2f;

  float lx = LP[((long)b * N1 + i) * 3 + 0];
  float ly = LP[((long)b * N1 + i) * 3 + 1];
  float lz = LP[((long)b * N1 + i) * 3 + 2];
  float tx = TP[((long)b * N2 + j) * 3 + 0];
  float ty = TP[((long)b * N2 + j) * 3 + 1];
  float tz = TP[((long)b * N2 + j) * 3 + 2];
  float dx = lx - tx, dy = ly - ty, dz = lz - tz;
  float s2 = dx * dx + dy * dy + dz * dz + 1e-10f;
  float draw = sqrtf(s2);
  bool clamped = draw < 0.5f;
  float dmv = clamped ? 1e10f : draw;

  float dm0 = LVDW[b * N1 + i] + TVDW[b * N2 + j] + B_raw;
  float dm0c = (dm0 < 1e-4f) ? 1.f : dm0;
  float valid = LNM[b * N1 + i] * TNM[b * N2 + j];

  float rr = dm0c / dmv;
  float r2 = rr * rr, r6 = r2 * r2 * r2;
  float fv = r6 * r6 - 2.f * r6;
  float evdw = A_vdw * (fminf(fv, 100.f) * valid);

  float dmd = dmv - dm0;
  long ii0 = ((long)b * 3) * N1 * N2 + (long)i * N2 + j;
  float I0 = II[ii0];
  float I1 = II[ii0 + (long)N1 * N2];
  float I2 = II[ii0 + 2L * N1 * N2];
  float hb2 = HBC[0] * HBC[0], hp2 = HPC[0] * HPC[0];
  float u0 = dmd * I0 / (-0.7f);
  float u1 = dmd * I1 / (-0.7f);
  float vv = (1.5f - dmd) * I2;
  float ehb = fminf(fmaxf(u0, 0.f), 1.f) * (-hb2);
  float emt = fminf(fmaxf(u1, 0.f), 1.f) * (-hb2);
  float ehp = fminf(fmaxf(vv, 0.f), 1.f) * (-hp2);

  float gx = 0.f, gy = 0.f, gz = 0.f, d2t = 0.f;
  if (!clamped) {
    float Ep = 0.f, Epp = 0.f;
    if (fv < 100.f) {
      float c = A_vdw * valid;
      Ep += c * (-12.f) * r6 * (r6 - 1.f) / draw;
      Epp += c * r6 * (156.f * r6 - 84.f) / s2;
    }
    if (u0 > 0.f && u0 < 1.f) Ep += hb2 * I0 * (1.f / 0.7f);
    if (u1 > 0.f && u1 < 1.f) Ep += hb2 * I1 * (1.f / 0.7f);
    if (vv > 0.f && vv < 1.f) Ep += hp2 * I2;
    float invd = 1.f / draw;
    gx = Ep * dx * invd;
    gy = Ep * dy * invd;
    gz = Ep * dz * invd;
    float T = dx + dy + dz;
    float tt = T * T / s2;
    d2t = Epp * tt + Ep * (3.f - tt) * invd;
  }

  float o0 = blockSum(evdw);
  float o1 = blockSum(ehb);
  float o2 = blockSum(emt);
  float o3 = blockSum(ehp);
  float o4 = blockSum(gx);
  float o5 = blockSum(gy);
  float o6 = blockSum(gz);
  float o7 = blockSum(d2t);
  if (j == 0) {
    float* p = PART + ((long)b * N1 + i) * 8;
    p[0] = o0; p[1] = o1; p[2] = o2; p[3] = o3;
    p[4] = o4; p[5] = o5; p[6] = o6; p[7] = o7;
  }
}

// final deterministic reduction + output assembly (34 floats)
__global__ void k_final(const float* __restrict__ PART, const float* __restrict__ ROT,
                        const float* __restrict__ RC, float* __restrict__ OUT) {
  const int N1 = N1C;
  __shared__ float s[8][8];
  int t = threadIdx.x;
  if (t < 64) {
    int b = t >> 3, k1 = t & 7;
    float acc = 0.f;
    for (int i = 0; i < N1; ++i) acc += PART[((long)b * N1 + i) * 8 + k1];
    s[b][k1] = acc;
  }
  __syncthreads();
  if (t == 0) {
    float rcc = RC[0] * RC[0];
    float der1 = 0.f, der2 = 0.f;
    for (int b = 0; b < 8; ++b) {
      float w = 1.f / (1.f + rcc * ROT[b]);
      OUT[b * 4 + 0] = s[b][0] * w;
      OUT[b * 4 + 1] = s[b][1] * w;
      OUT[b * 4 + 2] = s[b][2] * w;
      OUT[b * 4 + 3] = s[b][3] * w;
      for (int c = 0; c < 3; ++c) {
        float S = s[b][4 + c] * w;
        der1 += S * S;
      }
      der2 += s[b][7] * w;
    }
    OUT[32] = der1 / 24.f;
    OUT[33] = -der2 / 8.f;
  }
}

// ---------------------------------------------------------------------------
// Host-side orchestration
// ---------------------------------------------------------------------------
extern "C" void kernel_launch(void* const* d_in, const int* in_sizes, int n_in,
                              void* d_out, int out_size, void* d_ws, size_t ws_size,
                              hipStream_t stream) {
  (void)in_sizes; (void)n_in; (void)out_size; (void)ws_size;
  const int D = DC;

  const float* ligand_h   = (const float*)d_in[0];
  const float* ligand_adj = (const float*)d_in[1];
  const float* target_h   = (const float*)d_in[2];
  const float* target_adj = (const float*)d_in[3];
  const float* inter_ind  = (const float*)d_in[4];
  const float* ligand_pos = (const float*)d_in[5];
  const float* target_pos = (const float*)d_in[6];
  const float* rotor      = (const float*)d_in[7];
  const float* lvdw       = (const float*)d_in[8];
  const float* tvdw       = (const float*)d_in[9];
  const float* lnm        = (const float*)d_in[12];
  const float* tnm        = (const float*)d_in[13];
  const float* emb_w      = (const float*)d_in[14];
  const float* gat_w      = (const float*)d_in[15];
  const float* gat_b      = (const float*)d_in[16];
  const float* gat_att    = (const float*)d_in[17];
  const float* gat_gate_w = (const float*)d_in[18];
  const float* gat_gate_b = (const float*)d_in[19];
  const float* int_wt_w   = (const float*)d_in[20];
  const float* int_wt_b   = (const float*)d_in[21];
  const float* int_mt_w   = (const float*)d_in[22];
  const float* int_mt_b   = (const float*)d_in[23];
  const float* gru_w_ih   = (const float*)d_in[24];
  const float* gru_w_hh   = (const float*)d_in[25];
  const float* gru_b_ih   = (const float*)d_in[26];
  const float* gru_b_hh   = (const float*)d_in[27];
  const float* A_w1       = (const float*)d_in[28];
  const float* A_b1       = (const float*)d_in[29];
  const float* A_w2       = (const float*)d_in[30];
  const float* A_b2       = (const float*)d_in[31];
  const float* B_w1       = (const float*)d_in[32];
  const float* B_b1       = (const float*)d_in[33];
  const float* B_w2       = (const float*)d_in[34];
  const float* B_b2       = (const float*)d_in[35];
  const float* hb_c       = (const float*)d_in[36];
  const float* hp_c       = (const float*)d_in[37];
  const float* rc_c       = (const float*)d_in[38];

  // workspace carve (floats)
  float* w = (float*)d_ws;
  auto take = [&](size_t n) { float* p = w; w += n; return p; };
  float* LHA   = take((size_t)BB * N1C * DC);   // 131072
  float* LHB   = take((size_t)BB * N1C * DC);
  float* THA   = take((size_t)BB * N2C * DC);   // 262144
  float* THB   = take((size_t)BB * N2C * DC);
  float* NT    = take((size_t)BB * N2C * DC);
  float* E1    = take((size_t)BB * N2C * DC);
  float* EA    = take((size_t)BB * N2C * N2C);  // 524288
  float* OUTB  = take((size_t)BB * N2C * DC);
  float* ADJ12 = take((size_t)BB * N1C * N2C);  // 262144
  float* GI    = take((size_t)BB * N2C * 384);  // 786432
  float* GH    = take((size_t)BB * N2C * 384);
  float* PART  = take((size_t)BB * N1C * 8);
  // aliases (phase-disjoint)
  float* T1   = NT;
  float* M2   = E1;
  float* MSG  = OUTB;
  float* GIHT = EA;              // 3*128*384 = 147456 <= 524288
  float* GHHT = EA + 147456;
  float* UA   = GI;              // 131072
  float* UB   = GI + 131072;
  float* VAT  = GH;              // 262144
  float* VBT  = GH + 262144;

  auto LIN = [&](const float* X, const float* W_, const float* Bv, float* Y,
                 int K, int Dout, int rows, int rpb, long wbs, int act, int trans) {
    int grid = (rows + 7) / 8;
    k_linear<8><<<grid, 128, (size_t)8 * K * sizeof(float), stream>>>(
        X, W_, Bv, Y, K, Dout, rows, rpb, wbs, act, trans);
  };

  // interaction adjacency from geometry
  k_adj12<<<(BB * N1C * N2C + 255) / 256, 256, 0, stream>>>(ligand_pos, target_pos, ADJ12);

  // embeddings
  LIN(ligand_h, emb_w, nullptr, LHA, NHC, D, BB * N1C, BB * N1C, 0, 0, 0);
  LIN(target_h, emb_w, nullptr, THA, NHC, D, BB * N2C, BB * N2C, 0, 0, 0);

  float *cl = LHA, *al = LHB, *ct = THA, *at = THB;

  // GAT stacks
  auto GAT = [&](float*& cur, float*& alt, const float* adjp, int N) {
    int rows = BB * N;
    for (int l = 0; l < 3; ++l) {
      LIN(cur, gat_w + (size_t)l * D * D, gat_b + l * D, NT, D, D, rows, rows, 0, 0, 0);
      LIN(NT, gat_att + (size_t)l * D * D, nullptr, E1, D, D, rows, rows, 0, 0, 0);
      k_ea<<<dim3(N / 16, N / 16, BB), dim3(16, 16), 0, stream>>>(E1, NT, EA, N);
      k_softmax<<<rows, N, 0, stream>>>(EA, adjp, EA, N);
      LIN(EA, NT, nullptr, OUTB, N, D, rows, N, (long)N * D, 1, 0);
      k_gate<<<rows, 128, 0, stream>>>(cur, OUTB, gat_gate_w + l * 2 * D,
                                       gat_gate_b + l, alt);
      float* tmp = cur; cur = alt; alt = tmp;
    }
  };
  GAT(cl, al, ligand_adj, N1C);
  GAT(ct, at, target_adj, N2C);

  // GRU weight transposes (after GAT: EA is free)
  for (int l = 0; l < 3; ++l) {
    k_transpose<<<64, 256, 0, stream>>>(gru_w_ih + (size_t)l * 384 * 128,
                                        GIHT + (size_t)l * 128 * 384, 384, 128);
    k_transpose<<<64, 256, 0, stream>>>(gru_w_hh + (size_t)l * 384 * 128,
                                        GHHT + (size_t)l * 128 * 384, 384, 128);
  }

  // interaction layers
  for (int l = 0; l < 3; ++l) {
    const float* wt  = int_wt_w + (size_t)l * D * D;
    const float* wtb = int_wt_b + l * D;
    const float* mt  = int_mt_w + (size_t)l * D * D;
    const float* mtb = int_mt_b + l * D;
    const float* wihT = GIHT + (size_t)l * D * 384;
    const float* whhT = GHHT + (size_t)l * D * 384;
    const float* bih = gru_b_ih + l * 384;
    const float* bhh = gru_b_hh + l * 384;

    // ligand update (reads cl, ct)
    LIN(cl, wt, wtb, T1, D, D, BB * N1C, BB * N1C, 0, 0, 0);
    LIN(ct, mt, mtb, M2, D, D, BB * N2C, BB * N2C, 0, 0, 0);
    k_msg<<<dim3(N1C, BB), 128, N2C * sizeof(float), stream>>>(
        T1, M2, ADJ12, MSG, N1C, N2C, (long)N1C * N2C, (long)N2C, 1L);
    LIN(MSG, wihT, bih, GI, D, 384, BB * N1C, BB * N1C, 0, 0, 0);
    LIN(cl, whhT, bhh, GH, D, 384, BB * N1C, BB * N1C, 0, 0, 0);
    k_gru<<<BB * N1C, 128, 0, stream>>>(GI, GH, cl, al);

    // target update (reads ct, OLD cl)
    LIN(ct, wt, wtb, T1, D, D, BB * N2C, BB * N2C, 0, 0, 0);
    LIN(cl, mt, mtb, M2, D, D, BB * N1C, BB * N1C, 0, 0, 0);
    k_msg<<<dim3(N2C, BB), 128, N1C * sizeof(float), stream>>>(
        T1, M2, ADJ12, MSG, N2C, N1C, (long)N1C * N2C, 1L, (long)N2C);
    LIN(MSG, wihT, bih, GI, D, 384, BB * N2C, BB * N2C, 0, 0, 0);
    LIN(ct, whhT, bhh, GH, D, 384, BB * N2C, BB * N2C, 0, 0, 0);
    k_gru<<<BB * N2C, 128, 0, stream>>>(GI, GH, ct, at);

    { float* t = cl; cl = al; al = t; }
    { float* t = ct; ct = at; at = t; }
  }

  // pairwise feature precompute (U normal layout, V transposed [b][d][j])
  LIN(cl, A_w1, A_b1, UA, D, D, BB * N1C, BB * N1C, 0, 0, 0);
  LIN(ct, A_w1 + D * D, nullptr, VAT, D, D, BB * N2C, N2C, 0, 0, 1);
  LIN(cl, B_w1, B_b1, UB, D, D, BB * N1C, BB * N1C, 0, 0, 0);
  LIN(ct, B_w1 + D * D, nullptr, VBT, D, D, BB * N2C, N2C, 0, 0, 1);

  // pairwise physics + analytic derivatives
  k_pair<<<dim3(N1C, BB), 256, 0, stream>>>(UA, VAT, UB, VBT, A_w2, A_b2, B_w2,
                                            B_b2, ligand_pos, target_pos, lvdw,
                                            tvdw, lnm, tnm, inter_ind, hb_c,
                                            hp_c, PART);

  // final reduction -> 34 outputs
  k_final<<<1, 256, 0, stream>>>(PART, rotor, rc_c, (float*)d_out);
}

// Round 2
// 913.284 us; speedup vs baseline: 1.4088x; 1.4088x over previous
//
#include <hip/hip_runtime.h>
#include <math.h>

// ---------------------------------------------------------------------------
// Problem constants (B=8, N1=128, N2=256, D=128, L=3, NH=54)
// ---------------------------------------------------------------------------
#define BB 8
#define N1C 128
#define N2C 256
#define DC 128
#define NHC 54

// ---------------------------------------------------------------------------
// Reductions (wave64)
// ---------------------------------------------------------------------------
__device__ __forceinline__ float wredSum(float v) {
#pragma unroll
  for (int o = 32; o > 0; o >>= 1) v += __shfl_down(v, o);
  return v;
}
__device__ __forceinline__ float wredMax(float v) {
#pragma unroll
  for (int o = 32; o > 0; o >>= 1) v = fmaxf(v, __shfl_down(v, o));
  return v;
}
__device__ float blockSum(float v) {
  __shared__ float red[9];
  v = wredSum(v);
  int lane = threadIdx.x & 63, wid = threadIdx.x >> 6;
  __syncthreads();
  if (lane == 0) red[wid] = v;
  __syncthreads();
  if (threadIdx.x == 0) {
    float s = 0.f;
    int nw = (blockDim.x + 63) >> 6;
    for (int i = 0; i < nw; ++i) s += red[i];
    red[8] = s;
  }
  __syncthreads();
  return red[8];
}
__device__ float blockMax(float v) {
  __shared__ float redm[9];
  v = wredMax(v);
  int lane = threadIdx.x & 63, wid = threadIdx.x >> 6;
  __syncthreads();
  if (lane == 0) redm[wid] = v;
  __syncthreads();
  if (threadIdx.x == 0) {
    float s = -INFINITY;
    int nw = (blockDim.x + 63) >> 6;
    for (int i = 0; i < nw; ++i) s = fmaxf(s, redm[i]);
    redm[8] = s;
  }
  __syncthreads();
  return redm[8];
}

// ---------------------------------------------------------------------------
// Generic linear: Y = act(X @ W + bias).  X [rows][K], W [K][Dout] (row-major,
// optionally per-batch with stride wbs), 8 rows per block staged in LDS.
// trans=1 stores Y[b][d][row_in_batch] (for the transposed V features).
// ---------------------------------------------------------------------------
template <int RB>
__global__ void k_linear(const float* __restrict__ X, const float* __restrict__ W,
                         const float* __restrict__ bias, float* __restrict__ Y,
                         int K, int Dout, int rows, int rpb, long wbs, int act,
                         int trans) {
  int r0 = blockIdx.x * RB;
  extern __shared__ float xs[];  // RB*K
  for (int t = threadIdx.x; t < RB * K; t += blockDim.x) {
    int rr = r0 + t / K;
    xs[t] = (rr < rows) ? X[(long)rr * K + (t % K)] : 0.f;
  }
  __syncthreads();
  int b = r0 / rpb;  // RB always divides rpb in our uses
  const float* Wb = W + (long)b * wbs;
  for (int d = threadIdx.x; d < Dout; d += blockDim.x) {
    float acc[RB];
#pragma unroll
    for (int r = 0; r < RB; ++r) acc[r] = 0.f;
#pragma unroll 4
    for (int k = 0; k < K; ++k) {
      float wv = Wb[(long)k * Dout + d];
#pragma unroll
      for (int r = 0; r < RB; ++r) acc[r] += xs[r * K + k] * wv;
    }
    float bv = bias ? bias[d] : 0.f;
#pragma unroll
    for (int r = 0; r < RB; ++r) {
      int rr = r0 + r;
      if (rr < rows) {
        float v = acc[r] + bv;
        if (act) v = fmaxf(v, 0.f);
        if (!trans) {
          Y[(long)rr * Dout + d] = v;
        } else {
          int rin = rr - b * rpb;
          Y[((long)b * Dout + d) * rpb + rin] = v;
        }
      }
    }
  }
}

// ---------------------------------------------------------------------------
// ea[b,j,k] = e1_j . nt_k + nt_j . e1_k   (symmetrized attention logits)
// ---------------------------------------------------------------------------
__global__ void k_ea(const float* __restrict__ E1p, const float* __restrict__ NTp,
                     float* __restrict__ EAp, int N) {
  const int D = DC;
  int b = blockIdx.z;
  int j0 = blockIdx.y * 16, k0 = blockIdx.x * 16;
  int tj = threadIdx.y, tk = threadIdx.x;
  __shared__ float e1j[16][17], ntj[16][17], e1k[16][17], ntk[16][17];
  const float* E1b = E1p + (long)b * N * D;
  const float* NTb = NTp + (long)b * N * D;
  float acc = 0.f;
  for (int kk = 0; kk < D; kk += 16) {
    e1j[tj][tk] = E1b[(long)(j0 + tj) * D + kk + tk];
    ntj[tj][tk] = NTb[(long)(j0 + tj) * D + kk + tk];
    e1k[tj][tk] = E1b[(long)(k0 + tj) * D + kk + tk];
    ntk[tj][tk] = NTb[(long)(k0 + tj) * D + kk + tk];
    __syncthreads();
#pragma unroll
    for (int t = 0; t < 16; ++t)
      acc += e1j[tj][t] * ntk[tk][t] + ntj[tj][t] * e1k[tk][t];
    __syncthreads();
  }
  EAp[(long)b * N * N + (long)(j0 + tj) * N + k0 + tk] = acc;
}

// masked softmax over last dim, times adj (in-place capable)
__global__ void k_softmax(const float* __restrict__ EAin,
                          const float* __restrict__ ADJ, float* __restrict__ AW,
                          int N) {
  long row = blockIdx.x;
  int k = threadIdx.x;
  float a = ADJ[row * (long)N + k];
  float e = EAin[row * (long)N + k];
  float val = (a > 1e-6f) ? e : -9e15f;
  float m = blockMax(val);
  float ex = expf(val - m);
  float s = blockSum(ex);
  AW[row * (long)N + k] = ex / s * a;
}

// gated residual: y = g*x + (1-g)*out,  g = sigmoid([x,out].gw + gb)
__global__ void k_gate(const float* __restrict__ X, const float* __restrict__ OUT,
                       const float* __restrict__ GW, const float* __restrict__ GB,
                       float* __restrict__ Y) {
  const int D = DC;
  long r = blockIdx.x;
  int d = threadIdx.x;
  float x = X[r * D + d], o = OUT[r * D + d];
  float s = blockSum(x * GW[d] + o * GW[D + d]);
  float g = 1.f / (1.f + expf(-(s + GB[0])));
  Y[r * D + d] = g * x + (1.f - g) * o;
}

// adj12 from positions
__global__ void k_adj12(const float* __restrict__ LP, const float* __restrict__ TP,
                        float* __restrict__ AD) {
  long idx = (long)blockIdx.x * blockDim.x + threadIdx.x;
  if (idx >= (long)BB * N1C * N2C) return;
  int j = idx & (N2C - 1);
  long t = idx >> 8;
  int i = (int)(t & (N1C - 1));
  int b = (int)(t >> 7);
  float dx = LP[((long)b * N1C + i) * 3 + 0] - TP[((long)b * N2C + j) * 3 + 0];
  float dy = LP[((long)b * N1C + i) * 3 + 1] - TP[((long)b * N2C + j) * 3 + 1];
  float dz = LP[((long)b * N1C + i) * 3 + 2] - TP[((long)b * N2C + j) * 3 + 2];
  float d = sqrtf(dx * dx + dy * dy + dz * dz + 1e-10f);
  if (d < 0.5f) d = 1e10f;
  AD[idx] = (d <= 5.0f && d > 1e-3f) ? 1.f : 0.f;
}

// ---------------------------------------------------------------------------
// msg = relu(t1 + max_j(m2[j]*ev[i,j])) — LDS-tiled, MI rows of i per block,
// JT-wide j tiles, 4 independent accumulators per thread.
// grid (Ni/MI, B), block 256.
// ---------------------------------------------------------------------------
template <int MI, int JT>
__global__ __launch_bounds__(256) void k_msg2(
    const float* __restrict__ T1, const float* __restrict__ M2,
    const float* __restrict__ EV, float* __restrict__ MSG, int Ni, int Nj,
    long ev_bs, long ev_is, long ev_js) {
  const int D = DC;
  int b = blockIdx.y, i0 = blockIdx.x * MI;
  __shared__ float m2s[JT][DC];
  __shared__ float evs[MI][JT];
  int d = threadIdx.x & (DC - 1);
  int io = threadIdx.x >> 7;  // 0..1
  float acc[MI / 2];
#pragma unroll
  for (int r = 0; r < MI / 2; ++r) acc[r] = -INFINITY;
  const float* M2b = M2 + (long)b * Nj * D;
  for (int j0 = 0; j0 < Nj; j0 += JT) {
    __syncthreads();
    for (int t = threadIdx.x; t < JT * DC; t += 256)
      m2s[t >> 7][t & 127] = M2b[(long)(j0 + (t >> 7)) * D + (t & 127)];
    for (int t = threadIdx.x; t < MI * JT; t += 256) {
      int ii = t / JT, jj = t % JT;
      evs[ii][jj] =
          EV[(long)b * ev_bs + (long)(i0 + ii) * ev_is + (long)(j0 + jj) * ev_js];
    }
    __syncthreads();
#pragma unroll
    for (int jj = 0; jj < JT; ++jj) {
      float m2v = m2s[jj][d];
#pragma unroll
      for (int r = 0; r < MI / 2; ++r)
        acc[r] = fmaxf(acc[r], m2v * evs[io + 2 * r][jj]);
    }
  }
#pragma unroll
  for (int r = 0; r < MI / 2; ++r) {
    int i = i0 + io + 2 * r;
    long idx = ((long)b * Ni + i) * D + d;
    MSG[idx] = fmaxf(T1[idx] + acc[r], 0.f);
  }
}

// ---------------------------------------------------------------------------
// Fused GRU: gi = msg@WihT+bih, gh = h@WhhT+bhh, then GRU combine -> Y.
// 8 rows per block, 384 threads.
// ---------------------------------------------------------------------------
__global__ __launch_bounds__(384) void k_gruf(
    const float* __restrict__ MSGp, const float* __restrict__ Hp,
    const float* __restrict__ WihT, const float* __restrict__ WhhT,
    const float* __restrict__ bih, const float* __restrict__ bhh,
    float* __restrict__ Y) {
  const int D = DC;
  int r0 = blockIdx.x * 8;
  __shared__ float xs[8][DC], hs[8][DC];
  __shared__ float gis[8][384], ghs[8][384];
  for (int t = threadIdx.x; t < 8 * DC; t += 384) {
    int r = t >> 7, c = t & 127;
    xs[r][c] = MSGp[(long)(r0 + r) * D + c];
    hs[r][c] = Hp[(long)(r0 + r) * D + c];
  }
  __syncthreads();
  int dd = threadIdx.x;  // 0..383
  float ai[8], ah[8];
#pragma unroll
  for (int r = 0; r < 8; ++r) { ai[r] = 0.f; ah[r] = 0.f; }
#pragma unroll 2
  for (int k = 0; k < DC; ++k) {
    float wi = WihT[(long)k * 384 + dd];
    float wh = WhhT[(long)k * 384 + dd];
#pragma unroll
    for (int r = 0; r < 8; ++r) {
      ai[r] += xs[r][k] * wi;
      ah[r] += hs[r][k] * wh;
    }
  }
  float bi = bih[dd], bh = bhh[dd];
#pragma unroll
  for (int r = 0; r < 8; ++r) {
    gis[r][dd] = ai[r] + bi;
    ghs[r][dd] = ah[r] + bh;
  }
  __syncthreads();
  for (int t = threadIdx.x; t < 8 * DC; t += 384) {
    int r = t >> 7, d = t & 127;
    float ir = gis[r][d], iz = gis[r][d + 128], inn = gis[r][d + 256];
    float hr = ghs[r][d], hz = ghs[r][d + 128], hn = ghs[r][d + 256];
    float rg = 1.f / (1.f + expf(-(ir + hr)));
    float zg = 1.f / (1.f + expf(-(iz + hz)));
    float ng = tanhf(inn + rg * hn);
    Y[(long)(r0 + r) * D + d] = (1.f - zg) * ng + zg * hs[r][d];
  }
}

// ---------------------------------------------------------------------------
// Dual-head feature linear: Y1 = X@W1(+b1), Y2 = X@W2(+b2).  K=Dout=128.
// ---------------------------------------------------------------------------
template <int RB>
__global__ __launch_bounds__(128) void k_feat2(
    const float* __restrict__ X, const float* __restrict__ W1,
    const float* __restrict__ b1, const float* __restrict__ W2,
    const float* __restrict__ b2, float* __restrict__ Y1, float* __restrict__ Y2,
    int rpb, int trans) {
  int r0 = blockIdx.x * RB;
  __shared__ float xs[RB][DC];
  for (int t = threadIdx.x; t < RB * DC; t += 128)
    xs[t >> 7][t & 127] = X[(long)(r0 + (t >> 7)) * DC + (t & 127)];
  __syncthreads();
  int d = threadIdx.x;
  float a1[RB], a2[RB];
#pragma unroll
  for (int r = 0; r < RB; ++r) { a1[r] = 0.f; a2[r] = 0.f; }
#pragma unroll 2
  for (int k = 0; k < DC; ++k) {
    float w1 = W1[(long)k * DC + d];
    float w2 = W2[(long)k * DC + d];
#pragma unroll
    for (int r = 0; r < RB; ++r) {
      a1[r] += xs[r][k] * w1;
      a2[r] += xs[r][k] * w2;
    }
  }
  float bv1 = b1 ? b1[d] : 0.f, bv2 = b2 ? b2[d] : 0.f;
#pragma unroll
  for (int r = 0; r < RB; ++r) {
    int rr = r0 + r;
    float v1 = a1[r] + bv1, v2 = a2[r] + bv2;
    if (!trans) {
      Y1[(long)rr * DC + d] = v1;
      Y2[(long)rr * DC + d] = v2;
    } else {
      int b = rr / rpb, rin = rr - b * rpb;
      Y1[((long)b * DC + d) * rpb + rin] = v1;
      Y2[((long)b * DC + d) * rpb + rin] = v2;
    }
  }
}

// GRU combine (unused stand-alone path kept for reference-free fallback)
// transpose [R][C] -> [C][R]
__global__ void k_transpose(const float* __restrict__ in, float* __restrict__ out,
                            int R, int C) {
  for (long idx = (long)blockIdx.x * blockDim.x + threadIdx.x; idx < (long)R * C;
       idx += (long)gridDim.x * blockDim.x) {
    int r = (int)(idx / C), c = (int)(idx % C);
    out[(long)c * R + r] = in[idx];
  }
}

// ---------------------------------------------------------------------------
// Pairwise physics + analytic grad/Hessian partials.
// Per (b,i) block, 256 threads (j).  Writes 8 partials per (b,i):
// [vdw, hb, metal, hp, Sx, Sy, Sz, d2]
// ---------------------------------------------------------------------------
__global__ __launch_bounds__(256) void k_pair(
    const float* __restrict__ UA, const float* __restrict__ VAT,
    const float* __restrict__ UB, const float* __restrict__ VBT,
    const float* __restrict__ AW2, const float* __restrict__ AB2,
    const float* __restrict__ BW2, const float* __restrict__ BB2,
    const float* __restrict__ LP, const float* __restrict__ TP,
    const float* __restrict__ LVDW, const float* __restrict__ TVDW,
    const float* __restrict__ LNM, const float* __restrict__ TNM,
    const float* __restrict__ II, const float* __restrict__ HBC,
    const float* __restrict__ HPC, float* __restrict__ PART) {
  const int D = DC, N1 = N1C, N2 = N2C;
  int i = blockIdx.x, b = blockIdx.y, j = threadIdx.x;
  __shared__ float ua[128], ub[128], wa2[128], wb2[128];
  if (j < 128) {
    long rb = ((long)b * N1 + i) * D + j;
    ua[j] = UA[rb];
    ub[j] = UB[rb];
    wa2[j] = AW2[j];
    wb2[j] = BW2[j];
  }
  __syncthreads();
  const float* vat = VAT + (long)b * D * N2;
  const float* vbt = VBT + (long)b * D * N2;
  float dotA = 0.f, dotB = 0.f;
#pragma unroll 4
  for (int d = 0; d < D; ++d) {
    dotA += fmaxf(ua[d] + vat[(long)d * N2 + j], 0.f) * wa2[d];
    dotB += fmaxf(ub[d] + vbt[(long)d * N2 + j], 0.f) * wb2[d];
  }
  float A_raw = 1.f / (1.f + expf(-(dotA + AB2[0])));
  float A_vdw = A_raw * (0.0356f - 0.0178f) + 0.0178f;
  float B_raw = tanhf(dotB + BB2[0]) * 0.2f;

  float lx = LP[((long)b * N1 + i) * 3 + 0];
  float ly = LP[((long)b * N1 + i) * 3 + 1];
  float lz = LP[((long)b * N1 + i) * 3 + 2];
  float tx = TP[((long)b * N2 + j) * 3 + 0];
  float ty = TP[((long)b * N2 + j) * 3 + 1];
  float tz = TP[((long)b * N2 + j) * 3 + 2];
  float dx = lx - tx, dy = ly - ty, dz = lz - tz;
  float s2 = dx * dx + dy * dy + dz * dz + 1e-10f;
  float draw = sqrtf(s2);
  bool clamped = draw < 0.5f;
  float dmv = clamped ? 1e10f : draw;

  float dm0 = LVDW[b * N1 + i] + TVDW[b * N2 + j] + B_raw;
  float dm0c = (dm0 < 1e-4f) ? 1.f : dm0;
  float valid = LNM[b * N1 + i] * TNM[b * N2 + j];

  float rr = dm0c / dmv;
  float r2 = rr * rr, r6 = r2 * r2 * r2;
  float fv = r6 * r6 - 2.f * r6;
  float evdw = A_vdw * (fminf(fv, 100.f) * valid);

  float dmd = dmv - dm0;
  long ii0 = ((long)b * 3) * N1 * N2 + (long)i * N2 + j;
  float I0 = II[ii0];
  float I1 = II[ii0 + (long)N1 * N2];
  float I2 = II[ii0 + 2L * N1 * N2];
  float hb2 = HBC[0] * HBC[0], hp2 = HPC[0] * HPC[0];
  float u0 = dmd * I0 / (-0.7f);
  float u1 = dmd * I1 / (-0.7f);
  float vv = (1.5f - dmd) * I2;
  float ehb = fminf(fmaxf(u0, 0.f), 1.f) * (-hb2);
  float emt = fminf(fmaxf(u1, 0.f), 1.f) * (-hb2);
  float ehp = fminf(fmaxf(vv, 0.f), 1.f) * (-hp2);

  float gx = 0.f, gy = 0.f, gz = 0.f, d2t = 0.f;
  if (!clamped) {
    float Ep = 0.f, Epp = 0.f;
    if (fv < 100.f) {
      float c = A_vdw * valid;
      Ep += c * (-12.f) * r6 * (r6 - 1.f) / draw;
      Epp += c * r6 * (156.f * r6 - 84.f) / s2;
    }
    if (u0 > 0.f && u0 < 1.f) Ep += hb2 * I0 * (1.f / 0.7f);
    if (u1 > 0.f && u1 < 1.f) Ep += hb2 * I1 * (1.f / 0.7f);
    if (vv > 0.f && vv < 1.f) Ep += hp2 * I2;
    float invd = 1.f / draw;
    gx = Ep * dx * invd;
    gy = Ep * dy * invd;
    gz = Ep * dz * invd;
    float T = dx + dy + dz;
    float tt = T * T / s2;
    d2t = Epp * tt + Ep * (3.f - tt) * invd;
  }

  float o0 = blockSum(evdw);
  float o1 = blockSum(ehb);
  float o2 = blockSum(emt);
  float o3 = blockSum(ehp);
  float o4 = blockSum(gx);
  float o5 = blockSum(gy);
  float o6 = blockSum(gz);
  float o7 = blockSum(d2t);
  if (j == 0) {
    float* p = PART + ((long)b * N1 + i) * 8;
    p[0] = o0; p[1] = o1; p[2] = o2; p[3] = o3;
    p[4] = o4; p[5] = o5; p[6] = o6; p[7] = o7;
  }
}

// final deterministic reduction + output assembly (34 floats)
__global__ void k_final(const float* __restrict__ PART, const float* __restrict__ ROT,
                        const float* __restrict__ RC, float* __restrict__ OUT) {
  const int N1 = N1C;
  __shared__ float s[8][8];
  int t = threadIdx.x;
  if (t < 64) {
    int b = t >> 3, k1 = t & 7;
    float acc = 0.f;
    for (int i = 0; i < N1; ++i) acc += PART[((long)b * N1 + i) * 8 + k1];
    s[b][k1] = acc;
  }
  __syncthreads();
  if (t == 0) {
    float rcc = RC[0] * RC[0];
    float der1 = 0.f, der2 = 0.f;
    for (int b = 0; b < 8; ++b) {
      float w = 1.f / (1.f + rcc * ROT[b]);
      OUT[b * 4 + 0] = s[b][0] * w;
      OUT[b * 4 + 1] = s[b][1] * w;
      OUT[b * 4 + 2] = s[b][2] * w;
      OUT[b * 4 + 3] = s[b][3] * w;
      for (int c = 0; c < 3; ++c) {
        float S = s[b][4 + c] * w;
        der1 += S * S;
      }
      der2 += s[b][7] * w;
    }
    OUT[32] = der1 / 24.f;
    OUT[33] = -der2 / 8.f;
  }
}

// ---------------------------------------------------------------------------
// Host-side orchestration
// ---------------------------------------------------------------------------
extern "C" void kernel_launch(void* const* d_in, const int* in_sizes, int n_in,
                              void* d_out, int out_size, void* d_ws, size_t ws_size,
                              hipStream_t stream) {
  (void)in_sizes; (void)n_in; (void)out_size; (void)ws_size;
  const int D = DC;

  const float* ligand_h   = (const float*)d_in[0];
  const float* ligand_adj = (const float*)d_in[1];
  const float* target_h   = (const float*)d_in[2];
  const float* target_adj = (const float*)d_in[3];
  const float* inter_ind  = (const float*)d_in[4];
  const float* ligand_pos = (const float*)d_in[5];
  const float* target_pos = (const float*)d_in[6];
  const float* rotor      = (const float*)d_in[7];
  const float* lvdw       = (const float*)d_in[8];
  const float* tvdw       = (const float*)d_in[9];
  const float* lnm        = (const float*)d_in[12];
  const float* tnm        = (const float*)d_in[13];
  const float* emb_w      = (const float*)d_in[14];
  const float* gat_w      = (const float*)d_in[15];
  const float* gat_b      = (const float*)d_in[16];
  const float* gat_att    = (const float*)d_in[17];
  const float* gat_gate_w = (const float*)d_in[18];
  const float* gat_gate_b = (const float*)d_in[19];
  const float* int_wt_w   = (const float*)d_in[20];
  const float* int_wt_b   = (const float*)d_in[21];
  const float* int_mt_w   = (const float*)d_in[22];
  const float* int_mt_b   = (const float*)d_in[23];
  const float* gru_w_ih   = (const float*)d_in[24];
  const float* gru_w_hh   = (const float*)d_in[25];
  const float* gru_b_ih   = (const float*)d_in[26];
  const float* gru_b_hh   = (const float*)d_in[27];
  const float* A_w1       = (const float*)d_in[28];
  const float* A_b1       = (const float*)d_in[29];
  const float* A_w2       = (const float*)d_in[30];
  const float* A_b2       = (const float*)d_in[31];
  const float* B_w1       = (const float*)d_in[32];
  const float* B_b1       = (const float*)d_in[33];
  const float* B_w2       = (const float*)d_in[34];
  const float* B_b2       = (const float*)d_in[35];
  const float* hb_c       = (const float*)d_in[36];
  const float* hp_c       = (const float*)d_in[37];
  const float* rc_c       = (const float*)d_in[38];

  // workspace carve (floats)
  float* w = (float*)d_ws;
  auto take = [&](size_t n) { float* p = w; w += n; return p; };
  float* LHA   = take((size_t)BB * N1C * DC);   // 131072
  float* LHB   = take((size_t)BB * N1C * DC);
  float* THA   = take((size_t)BB * N2C * DC);   // 262144
  float* THB   = take((size_t)BB * N2C * DC);
  float* NT    = take((size_t)BB * N2C * DC);
  float* E1    = take((size_t)BB * N2C * DC);
  float* EA    = take((size_t)BB * N2C * N2C);  // 524288
  float* OUTB  = take((size_t)BB * N2C * DC);
  float* ADJ12 = take((size_t)BB * N1C * N2C);  // 262144
  float* GI    = take((size_t)BB * N2C * 384);  // 786432
  float* GH    = take((size_t)BB * N2C * 384);
  float* PART  = take((size_t)BB * N1C * 8);
  // aliases (phase-disjoint)
  float* T1   = NT;
  float* M2   = E1;
  float* MSG  = OUTB;
  float* GIHT = EA;              // 3*128*384 = 147456 <= 524288
  float* GHHT = EA + 147456;
  float* UA   = GI;              // 131072
  float* UB   = GI + 131072;
  float* VAT  = GH;              // 262144
  float* VBT  = GH + 262144;

  auto LIN = [&](const float* X, const float* W_, const float* Bv, float* Y,
                 int K, int Dout, int rows, int rpb, long wbs, int act, int trans) {
    int grid = (rows + 7) / 8;
    k_linear<8><<<grid, 128, (size_t)8 * K * sizeof(float), stream>>>(
        X, W_, Bv, Y, K, Dout, rows, rpb, wbs, act, trans);
  };

  // interaction adjacency from geometry
  k_adj12<<<(BB * N1C * N2C + 255) / 256, 256, 0, stream>>>(ligand_pos, target_pos, ADJ12);

  // embeddings
  LIN(ligand_h, emb_w, nullptr, LHA, NHC, D, BB * N1C, BB * N1C, 0, 0, 0);
  LIN(target_h, emb_w, nullptr, THA, NHC, D, BB * N2C, BB * N2C, 0, 0, 0);

  float *cl = LHA, *al = LHB, *ct = THA, *at = THB;

  // GAT stacks
  auto GAT = [&](float*& cur, float*& alt, const float* adjp, int N) {
    int rows = BB * N;
    for (int l = 0; l < 3; ++l) {
      LIN(cur, gat_w + (size_t)l * D * D, gat_b + l * D, NT, D, D, rows, rows, 0, 0, 0);
      LIN(NT, gat_att + (size_t)l * D * D, nullptr, E1, D, D, rows, rows, 0, 0, 0);
      k_ea<<<dim3(N / 16, N / 16, BB), dim3(16, 16), 0, stream>>>(E1, NT, EA, N);
      k_softmax<<<rows, N, 0, stream>>>(EA, adjp, EA, N);
      LIN(EA, NT, nullptr, OUTB, N, D, rows, N, (long)N * D, 1, 0);
      k_gate<<<rows, 128, 0, stream>>>(cur, OUTB, gat_gate_w + l * 2 * D,
                                       gat_gate_b + l, alt);
      float* tmp = cur; cur = alt; alt = tmp;
    }
  };
  GAT(cl, al, ligand_adj, N1C);
  GAT(ct, at, target_adj, N2C);

  // GRU weight transposes (after GAT: EA is free)
  for (int l = 0; l < 3; ++l) {
    k_transpose<<<64, 256, 0, stream>>>(gru_w_ih + (size_t)l * 384 * 128,
                                        GIHT + (size_t)l * 128 * 384, 384, 128);
    k_transpose<<<64, 256, 0, stream>>>(gru_w_hh + (size_t)l * 384 * 128,
                                        GHHT + (size_t)l * 128 * 384, 384, 128);
  }

  // interaction layers
  for (int l = 0; l < 3; ++l) {
    const float* wt  = int_wt_w + (size_t)l * D * D;
    const float* wtb = int_wt_b + l * D;
    const float* mt  = int_mt_w + (size_t)l * D * D;
    const float* mtb = int_mt_b + l * D;
    const float* wihT = GIHT + (size_t)l * D * 384;
    const float* whhT = GHHT + (size_t)l * D * 384;
    const float* bih = gru_b_ih + l * 384;
    const float* bhh = gru_b_hh + l * 384;

    // ligand update (reads cl, ct)
    LIN(cl, wt, wtb, T1, D, D, BB * N1C, BB * N1C, 0, 0, 0);
    LIN(ct, mt, mtb, M2, D, D, BB * N2C, BB * N2C, 0, 0, 0);
    k_msg2<8, 32><<<dim3(N1C / 8, BB), 256, 0, stream>>>(
        T1, M2, ADJ12, MSG, N1C, N2C, (long)N1C * N2C, (long)N2C, 1L);
    k_gruf<<<BB * N1C / 8, 384, 0, stream>>>(MSG, cl, wihT, whhT, bih, bhh, al);

    // target update (reads ct, OLD cl)
    LIN(ct, wt, wtb, T1, D, D, BB * N2C, BB * N2C, 0, 0, 0);
    LIN(cl, mt, mtb, M2, D, D, BB * N1C, BB * N1C, 0, 0, 0);
    k_msg2<8, 32><<<dim3(N2C / 8, BB), 256, 0, stream>>>(
        T1, M2, ADJ12, MSG, N2C, N1C, (long)N1C * N2C, 1L, (long)N2C);
    k_gruf<<<BB * N2C / 8, 384, 0, stream>>>(MSG, ct, wihT, whhT, bih, bhh, at);

    { float* t = cl; cl = al; al = t; }
    { float* t = ct; ct = at; at = t; }
  }

  // pairwise feature precompute (U normal layout, V transposed [b][d][j])
  k_feat2<8><<<BB * N1C / 8, 128, 0, stream>>>(cl, A_w1, A_b1, B_w1, B_b1, UA, UB,
                                               BB * N1C, 0);
  k_feat2<8><<<BB * N2C / 8, 128, 0, stream>>>(ct, A_w1 + D * D, nullptr,
                                               B_w1 + D * D, nullptr, VAT, VBT,
                                               N2C, 1);

  // pairwise physics + analytic derivatives
  k_pair<<<dim3(N1C, BB), 256, 0, stream>>>(UA, VAT, UB, VBT, A_w2, A_b2, B_w2,
                                            B_b2, ligand_pos, target_pos, lvdw,
                                            tvdw, lnm, tnm, inter_ind, hb_c,
                                            hp_c, PART);

  // final reduction -> 34 outputs
  k_final<<<1, 256, 0, stream>>>(PART, rotor, rc_c, (float*)d_out);
}